// Round 9
// baseline (276.924 us; speedup 1.0000x reference)
//
#include <hip/hip_runtime.h>
#include <cstdio>

typedef __attribute__((ext_vector_type(8))) short short8;
typedef __attribute__((ext_vector_type(4))) float f32x4;

// ---------- helpers ----------

__device__ __forceinline__ unsigned short bf16r(float f) {
  union { float f; unsigned int u; } x; x.f = f;
  unsigned int r = x.u + 0x7fffu + ((x.u >> 16) & 1u);
  return (unsigned short)(r >> 16);
}

__device__ __forceinline__ float bf16f(unsigned short h) {
  union { unsigned int u; float f; } x; x.u = ((unsigned int)h) << 16;
  return x.f;
}

__device__ __forceinline__ void gload_lds16(const void* g, void* l) {
  __builtin_amdgcn_global_load_lds((const __attribute__((address_space(1))) void*)g,
                                   (__attribute__((address_space(3))) void*)l,
                                   16, 0, 0);
}

__device__ __forceinline__ short8 pack_bf16(float4 f0, float4 f1) {
  short8 h;
  h[0] = (short)bf16r(f0.x); h[1] = (short)bf16r(f0.y);
  h[2] = (short)bf16r(f0.z); h[3] = (short)bf16r(f0.w);
  h[4] = (short)bf16r(f1.x); h[5] = (short)bf16r(f1.y);
  h[6] = (short)bf16r(f1.z); h[7] = (short)bf16r(f1.w);
  return h;
}

// ---------- q_w [4096][4096] f32 -> qwt2 [4096(j)][8192] bf16: cols 0..4095 = hi(q_w^T), 4096.. = lo ----------

__global__ void transpose_hilo(const float* __restrict__ in, unsigned short* __restrict__ out) {
  __shared__ float tile[64][65];
  const int j0 = blockIdx.x * 64, i0 = blockIdx.y * 64;
  const int tx = threadIdx.x & 15, ty = threadIdx.x >> 4;
  #pragma unroll
  for (int w = 0; w < 4; ++w) {
    int r = ty + w * 16;
    float4 v = *reinterpret_cast<const float4*>(in + (size_t)(i0 + r) * 4096 + j0 + tx * 4);
    tile[r][tx * 4 + 0] = v.x; tile[r][tx * 4 + 1] = v.y;
    tile[r][tx * 4 + 2] = v.z; tile[r][tx * 4 + 3] = v.w;
  }
  __syncthreads();
  #pragma unroll
  for (int w = 0; w < 4; ++w) {
    int r = ty + w * 16;   // j offset within tile
    float v0 = tile[tx * 4 + 0][r], v1 = tile[tx * 4 + 1][r];
    float v2 = tile[tx * 4 + 2][r], v3 = tile[tx * 4 + 3][r];
    ushort4 hi, lo;
    hi.x = bf16r(v0); lo.x = bf16r(v0 - bf16f(hi.x));
    hi.y = bf16r(v1); lo.y = bf16r(v1 - bf16f(hi.y));
    hi.z = bf16r(v2); lo.z = bf16r(v2 - bf16f(hi.z));
    hi.w = bf16r(v3); lo.w = bf16r(v3 - bf16f(hi.w));
    *reinterpret_cast<ushort4*>(out + (size_t)(j0 + r) * 8192 + i0 + tx * 4) = hi;
    *reinterpret_cast<ushort4*>(out + (size_t)(j0 + r) * 8192 + 4096 + i0 + tx * 4) = lo;
  }
}

// ---------- k_cache [100][4096] f32 -> kpad2 [128][8192] bf16 duplicated ([kpad|kpad]), rows>=100 zero ----------

__global__ void build_pad_dup(const float* __restrict__ src, unsigned short* __restrict__ dst) {
  int idx = blockIdx.x * blockDim.x + threadIdx.x;   // over 128*4096
  if (idx >= 128 * 4096) return;
  int l = idx >> 12, i = idx & 4095;
  float v = (l < 100) ? src[idx] : 0.f;
  unsigned short b = bf16r(v);
  dst[(size_t)l * 8192 + i] = b;
  dst[(size_t)l * 8192 + 4096 + i] = b;
}

// ---------- v_cache [100][4096] f32 -> vpad [128][4096] bf16, rows>=100 zero ----------

__global__ void build_pad128(const float* __restrict__ src, unsigned short* __restrict__ dst) {
  int idx = blockIdx.x * blockDim.x + threadIdx.x;
  if (idx >= 128 * 4096) return;
  int row = idx >> 12;
  float v = (row < 100) ? src[idx] : 0.f;
  dst[idx] = bf16r(v);
}

// ---------- sbias[l] = q_b . k_cache[l] (f32, exact), 0 for l>=100 ----------

__global__ void kq_bias(const float* __restrict__ kc, const float* __restrict__ qb,
                        float* __restrict__ sbias) {
  int l = blockIdx.x;            // 0..127
  int lane = threadIdx.x;        // 64
  float s = 0.f;
  if (l < 100) {
    for (int i = lane * 4; i < 4096; i += 256) {
      float4 k = *reinterpret_cast<const float4*>(kc + (size_t)l * 4096 + i);
      float4 q = *reinterpret_cast<const float4*>(qb + i);
      s += k.x * q.x + k.y * q.y + k.z * q.z + k.w * q.w;
    }
  }
  #pragma unroll
  for (int off = 1; off < 64; off <<= 1) s += __shfl_xor(s, off);
  if (lane == 0) sbias[l] = s;
}

// ---------- DIRECT streaming GEMM (f32 A, depth-2 E/O register pipeline) ----------
// No LDS, no barriers. Wave = 32 rows x NFRAG*16 cols; block = 4 waves = 128 rows.
// NPLANES>1: B has NPLANES stacked plane blocks of NFRAG*16 rows; all planes
// accumulate into the same acc (exact f32 fold). grid (KSPLIT, M/128).
// Cpart[ks][M][NFRAG*16] f32. kchunk/32 must be even and >= 2.

template<int NFRAG, int NPLANES>
__global__ __launch_bounds__(256)
void gemm_direct2(const float* __restrict__ A,
                  const unsigned short* __restrict__ B,
                  float* __restrict__ Cpart,
                  int M, int Kstride, int kchunk) {
  const int tid = threadIdx.x, wave = tid >> 6, lane = tid & 63;
  const int ks = blockIdx.x, mblk = blockIdx.y;
  const size_t row0 = (size_t)mblk * 128 + wave * 32;
  const int k0 = ks * kchunk;
  const int fr = lane & 15, kq = lane >> 4;

  const float* Ap0 = A + (row0 + fr) * (size_t)Kstride + k0 + kq * 8;
  const float* Ap1 = Ap0 + (size_t)16 * Kstride;
  const unsigned short* Bp = B + (size_t)fr * Kstride + k0 + kq * 8;
  const int nsteps = kchunk >> 5;

  f32x4 acc[2][NFRAG] = {};

  float4 eA0, eA1, eA2, eA3, oA0, oA1, oA2, oA3;
#define LOADA(p0, p1, p2, p3, kk) do { const int _k = (kk) * 32; \
    p0 = *reinterpret_cast<const float4*>(Ap0 + _k); \
    p1 = *reinterpret_cast<const float4*>(Ap0 + _k + 4); \
    p2 = *reinterpret_cast<const float4*>(Ap1 + _k); \
    p3 = *reinterpret_cast<const float4*>(Ap1 + _k + 4); } while (0)

#define MMASTEP(a0, a1, kk) do { \
    _Pragma("unroll") \
    for (int ni = 0; ni < NFRAG; ++ni) { \
      _Pragma("unroll") \
      for (int p = 0; p < NPLANES; ++p) { \
        short8 b = *reinterpret_cast<const short8*>(Bp + (size_t)((p * NFRAG + ni) * 16) * Kstride + (kk) * 32); \
        acc[0][ni] = __builtin_amdgcn_mfma_f32_16x16x32_bf16(a0, b, acc[0][ni], 0, 0, 0); \
        acc[1][ni] = __builtin_amdgcn_mfma_f32_16x16x32_bf16(a1, b, acc[1][ni], 0, 0, 0); \
      } } } while (0)

  LOADA(eA0, eA1, eA2, eA3, 0);
  LOADA(oA0, oA1, oA2, oA3, 1);

  for (int k = 0; k < nsteps; k += 2) {
    {
      short8 a0 = pack_bf16(eA0, eA1), a1 = pack_bf16(eA2, eA3);
      if (k + 2 < nsteps) LOADA(eA0, eA1, eA2, eA3, k + 2);
      MMASTEP(a0, a1, k);
    }
    {
      short8 a0 = pack_bf16(oA0, oA1), a1 = pack_bf16(oA2, oA3);
      if (k + 3 < nsteps) LOADA(oA0, oA1, oA2, oA3, k + 3);
      MMASTEP(a0, a1, k + 1);
    }
  }
#undef LOADA
#undef MMASTEP

  const int N = NFRAG * 16;
  float* Cp = Cpart + (size_t)ks * M * N;
  const int orow = (lane >> 4) * 4;
  const int ocol = lane & 15;
  #pragma unroll
  for (int mi = 0; mi < 2; ++mi) {
    #pragma unroll
    for (int ni = 0; ni < NFRAG; ++ni) {
      size_t r0 = row0 + mi * 16 + orow;
      size_t c  = (size_t)ni * 16 + ocol;
      #pragma unroll
      for (int j = 0; j < 4; ++j)
        Cp[(r0 + j) * (size_t)N + c] = acc[mi][ni][j];
    }
  }
}

// ---------- DIRECT streaming GEMM, bf16 A (no cvt), same pipeline (KQ^T) ----------

template<int NFRAG>
__global__ __launch_bounds__(256)
void gemm_direct_bb(const unsigned short* __restrict__ A,
                    const unsigned short* __restrict__ B,
                    float* __restrict__ Cpart,
                    int M, int Kstride, int kchunk) {
  const int tid = threadIdx.x, wave = tid >> 6, lane = tid & 63;
  const int ks = blockIdx.x, mblk = blockIdx.y;
  const size_t row0 = (size_t)mblk * 128 + wave * 32;
  const int k0 = ks * kchunk;
  const int fr = lane & 15, kq = lane >> 4;

  const unsigned short* Ap0 = A + (row0 + fr) * (size_t)Kstride + k0 + kq * 8;
  const unsigned short* Ap1 = Ap0 + (size_t)16 * Kstride;
  const unsigned short* Bp = B + (size_t)fr * Kstride + k0 + kq * 8;
  const int nsteps = kchunk >> 5;

  f32x4 acc[2][NFRAG] = {};
  short8 eA0, eA1, oA0, oA1;

#define LOADA(p0, p1, kk) do { const int _k = (kk) * 32; \
    p0 = *reinterpret_cast<const short8*>(Ap0 + _k); \
    p1 = *reinterpret_cast<const short8*>(Ap1 + _k); } while (0)

#define MMASTEP(a0, a1, kk) do { \
    _Pragma("unroll") \
    for (int ni = 0; ni < NFRAG; ++ni) { \
      short8 b = *reinterpret_cast<const short8*>(Bp + (size_t)(ni * 16) * Kstride + (kk) * 32); \
      acc[0][ni] = __builtin_amdgcn_mfma_f32_16x16x32_bf16(a0, b, acc[0][ni], 0, 0, 0); \
      acc[1][ni] = __builtin_amdgcn_mfma_f32_16x16x32_bf16(a1, b, acc[1][ni], 0, 0, 0); \
    } } while (0)

  LOADA(eA0, eA1, 0);
  LOADA(oA0, oA1, 1);

  for (int k = 0; k < nsteps; k += 2) {
    {
      short8 a0 = eA0, a1 = eA1;
      if (k + 2 < nsteps) LOADA(eA0, eA1, k + 2);
      MMASTEP(a0, a1, k);
    }
    {
      short8 a0 = oA0, a1 = oA1;
      if (k + 3 < nsteps) LOADA(oA0, oA1, k + 3);
      MMASTEP(a0, a1, k + 1);
    }
  }
#undef LOADA
#undef MMASTEP

  const int N = NFRAG * 16;
  float* Cp = Cpart + (size_t)ks * M * N;
  const int orow = (lane >> 4) * 4;
  const int ocol = lane & 15;
  #pragma unroll
  for (int mi = 0; mi < 2; ++mi) {
    #pragma unroll
    for (int ni = 0; ni < NFRAG; ++ni) {
      size_t r0 = row0 + mi * 16 + orow;
      size_t c  = (size_t)ni * 16 + ocol;
      #pragma unroll
      for (int j = 0; j < 4; ++j)
        Cp[(r0 + j) * (size_t)N + c] = acc[mi][ni][j];
    }
  }
}

// ---------- KQ reduce: sum 16 KQ^T partials [4096(j)][128(l)], transpose, hi/lo -> KQ2 [256][4096] ----------

__global__ void kq_reduce2(const float* __restrict__ P, unsigned short* __restrict__ KQ2) {
  int idx = blockIdx.x * blockDim.x + threadIdx.x;   // over 4096*128, idx = j*128 + l
  if (idx >= 4096 * 128) return;
  float s = 0.f;
  #pragma unroll
  for (int ks = 0; ks < 16; ++ks) s += P[(size_t)ks * 4096 * 128 + idx];
  unsigned short hi = bf16r(s);
  unsigned short lo = bf16r(s - bf16f(hi));
  int j = idx >> 7, l = idx & 127;
  KQ2[(size_t)l * 4096 + j]         = hi;
  KQ2[(size_t)(l + 128) * 4096 + j] = lo;
}

// ---------- softmax: sum 8 ks-partials (width 128, planes pre-folded) + bias -> [W|W] bf16 [rows][256] ----------

__global__ void softmax_fused2(const float* __restrict__ Spart, const float* __restrict__ sbias,
                               unsigned short* __restrict__ W2, int rows) {
  int wave = threadIdx.x >> 6;
  int lane = threadIdx.x & 63;
  int row = blockIdx.x * (blockDim.x >> 6) + wave;
  if (row >= rows) return;
  const float scale = 0.088388347648318447f;   // 1/sqrt(128)
  float sx = 0.f, sy = 0.f;
  #pragma unroll
  for (int ks = 0; ks < 8; ++ks) {
    float2 p = reinterpret_cast<const float2*>(Spart + ((size_t)ks * rows + row) * 128)[lane];
    sx += p.x; sy += p.y;
  }
  float2 bb = reinterpret_cast<const float2*>(sbias)[lane];
  sx += bb.x; sy += bb.y;
  int c0 = lane * 2, c1 = c0 + 1;
  float s0 = (c0 <= 100) ? sx * scale : -1e30f;
  float s1 = (c1 <= 100) ? sy * scale : -1e30f;
  float m = fmaxf(s0, s1);
  #pragma unroll
  for (int off = 1; off < 64; off <<= 1) m = fmaxf(m, __shfl_xor(m, off));
  float e0 = (c0 <= 100) ? __expf(s0 - m) : 0.f;
  float e1 = (c1 <= 100) ? __expf(s1 - m) : 0.f;
  float sum = e0 + e1;
  #pragma unroll
  for (int off = 1; off < 64; off <<= 1) sum += __shfl_xor(sum, off);
  float inv = 1.f / sum;
  ushort2 o;
  o.x = bf16r(e0 * inv);
  o.y = bf16r(e1 * inv);
  reinterpret_cast<ushort2*>(W2 + (size_t)row * 256)[lane] = o;
  reinterpret_cast<ushort2*>(W2 + (size_t)row * 256 + 128)[lane] = o;
}

// ---------- VO reduce: sum 16 partials [4096][128], split hi/lo -> VOT2 [4096][256] bf16 ----------

__global__ void vo_reduce(const float* __restrict__ VOpart, unsigned short* __restrict__ VOT2) {
  int idx = blockIdx.x * blockDim.x + threadIdx.x;   // over 4096*128, idx = o*128 + l
  if (idx >= 4096 * 128) return;
  float s = 0.f;
  #pragma unroll
  for (int ks = 0; ks < 16; ++ks) s += VOpart[(size_t)ks * 4096 * 128 + idx];
  unsigned short hi = bf16r(s);
  unsigned short lo = bf16r(s - bf16f(hi));
  int o = idx >> 7, l = idx & 127;
  VOT2[(size_t)o * 256 + l]       = hi;
  VOT2[(size_t)o * 256 + 128 + l] = lo;
}

// ---------- m97-style 128^2 NT GEMM (final: out = W2 @ VOT2^T + out_b) ----------

template<bool ADD_BIAS, bool OUT_F32>
__global__ void gemm_nt(const unsigned short* __restrict__ A,
                        const unsigned short* __restrict__ B,
                        const float* __restrict__ bias,
                        void* __restrict__ Cout,
                        int M, int N, int K) {
  __shared__ unsigned short As[128][32];
  __shared__ unsigned short Bs[128][32];

  const int tid  = threadIdx.x;
  const int wave = tid >> 6;
  const int lane = tid & 63;
  const int wm = wave >> 1;
  const int wn = wave & 1;
  const size_t rowA0 = (size_t)blockIdx.y * 128;
  const size_t colB0 = (size_t)blockIdx.x * 128;

  f32x4 acc[4][4] = {};

  const int sr = wave * 16 + (lane >> 2);
  const int sc = (lane & 3) << 3;

  const unsigned short* Ap0 = A + (rowA0 + sr) * (size_t)K + sc;
  const unsigned short* Ap1 = A + (rowA0 + 64 + sr) * (size_t)K + sc;
  const unsigned short* Bp0 = B + (colB0 + sr) * (size_t)K + sc;
  const unsigned short* Bp1 = B + (colB0 + 64 + sr) * (size_t)K + sc;
  unsigned short* AsD0 = &As[wave * 16][0];
  unsigned short* AsD1 = &As[64 + wave * 16][0];
  unsigned short* BsD0 = &Bs[wave * 16][0];
  unsigned short* BsD1 = &Bs[64 + wave * 16][0];

  const int fr = lane & 15;
  const int fk = (lane >> 4) << 3;

  for (int k0 = 0; k0 < K; k0 += 32) {
    gload_lds16(Ap0 + k0, AsD0);
    gload_lds16(Ap1 + k0, AsD1);
    gload_lds16(Bp0 + k0, BsD0);
    gload_lds16(Bp1 + k0, BsD1);
    __syncthreads();

    short8 av[4], bv[4];
    #pragma unroll
    for (int mi = 0; mi < 4; ++mi)
      av[mi] = *reinterpret_cast<const short8*>(&As[wm * 64 + mi * 16 + fr][fk]);
    #pragma unroll
    for (int ni = 0; ni < 4; ++ni)
      bv[ni] = *reinterpret_cast<const short8*>(&Bs[wn * 64 + ni * 16 + fr][fk]);
    #pragma unroll
    for (int mi = 0; mi < 4; ++mi)
      #pragma unroll
      for (int ni = 0; ni < 4; ++ni)
        acc[mi][ni] = __builtin_amdgcn_mfma_f32_16x16x32_bf16(av[mi], bv[ni], acc[mi][ni], 0, 0, 0);
    __syncthreads();
  }

  const int orow = (lane >> 4) * 4;
  const int ocol = lane & 15;
  #pragma unroll
  for (int mi = 0; mi < 4; ++mi) {
    #pragma unroll
    for (int ni = 0; ni < 4; ++ni) {
      size_t r0 = rowA0 + wm * 64 + mi * 16 + orow;
      size_t c  = colB0 + wn * 64 + ni * 16 + ocol;
      float bv_ = ADD_BIAS ? bias[c] : 0.f;
      #pragma unroll
      for (int j = 0; j < 4; ++j) {
        float v = acc[mi][ni][j] + bv_;
        if (OUT_F32) ((float*)Cout)[(r0 + j) * (size_t)N + c] = v;
        else         ((unsigned short*)Cout)[(r0 + j) * (size_t)N + c] = bf16r(v);
      }
    }
  }
}

// ---------- launch ----------

extern "C" void kernel_launch(void* const* d_in, const int* in_sizes, int n_in,
                              void* d_out, int out_size, void* d_ws, size_t ws_size,
                              hipStream_t stream) {
  const float* x       = (const float*)d_in[0];   // [8192,4096]
  const float* q_w     = (const float*)d_in[1];   // [4096,4096]
  const float* q_b     = (const float*)d_in[2];   // [4096]
  const float* k_cache = (const float*)d_in[3];   // [100,4096]
  const float* v_cache = (const float*)d_in[4];   // [100,4096]
  const float* out_w   = (const float*)d_in[5];   // [4096,4096]
  const float* out_b   = (const float*)d_in[6];   // [4096]
  float* out = (float*)d_out;

  const int M = 8192, H = 4096;

  char* ws = (char*)d_ws;
  size_t off = 0;
  auto alloc = [&](size_t bytes) { void* p = ws + off; off += (bytes + 255) & ~(size_t)255; return p; };
  unsigned short* qwt2   = (unsigned short*)alloc((size_t)H * 8192 * 2);   // 67 MB  q_w^T hi|lo
  unsigned short* kpad2  = (unsigned short*)alloc((size_t)128 * 8192 * 2); // 2 MB   [kpad|kpad]
  unsigned short* vpad   = (unsigned short*)alloc((size_t)128 * H * 2);    // 1 MB
  float*          sbias  = (float*)alloc(128 * 4);
  unsigned short* KQ2    = (unsigned short*)alloc((size_t)256 * H * 2);    // 2 MB   [KQ_hi;KQ_lo]
  unsigned short* W2     = (unsigned short*)alloc((size_t)M * 256 * 2);    // 4 MB   [W|W]
  unsigned short* VOT2   = (unsigned short*)alloc((size_t)H * 256 * 2);    // 2 MB   [VO^T hi|lo]
  float*          scratch= (float*)alloc((size_t)34 << 20);                // 34 MB  partials
  if (ws_size < off) { fprintf(stderr, "ws too small: need %zu have %zu\n", off, ws_size); return; }

  // 1) weight/cache preprocessing
  transpose_hilo<<<dim3(64, 64), 256, 0, stream>>>(q_w, qwt2);
  build_pad_dup<<<2048, 256, 0, stream>>>(k_cache, kpad2);
  build_pad128<<<2048, 256, 0, stream>>>(v_cache, vpad);
  kq_bias<<<128, 64, 0, stream>>>(k_cache, q_b, sbias);

  // 2) KQ^T = qwt2 (stream, bf16) x kpad2^T (L2): direct kernel, ksplit 16 -> 512 blocks
  gemm_direct_bb<8><<<dim3(16, 32), 256, 0, stream>>>(qwt2, kpad2, scratch, H, 8192, 512);
  kq_reduce2<<<2048, 256, 0, stream>>>(scratch, KQ2);

  // 3) S = x (stream, f32) @ KQ2^T with in-kernel hi/lo fold: ksplit 8 -> 512 blocks
  gemm_direct2<8, 2><<<dim3(8, 64), 256, 0, stream>>>(x, KQ2, scratch, M, H, 512);

  // 4) softmax (8 ks partials, width 128) -> W2 [8192][256] dup
  softmax_fused2<<<M / 4, 256, 0, stream>>>(scratch, sbias, W2, M);

  // 5) VO^T = out_w (stream, f32) @ vpad^T: ksplit 16 -> 512 blocks
  gemm_direct2<8, 1><<<dim3(16, 32), 256, 0, stream>>>(out_w, vpad, scratch, H, H, 256);
  vo_reduce<<<2048, 256, 0, stream>>>(scratch, VOT2);

  // 6) out = W2 @ VOT2^T + out_b  (K=256: [W|W] x [hi|lo])
  gemm_nt<true, true><<<dim3(32, 64), 256, 0, stream>>>(W2, VOT2, out_b, out, M, H, 256);
}

// Round 10
// 215.231 us; speedup vs baseline: 1.2866x; 1.2866x over previous
//
#include <hip/hip_runtime.h>
#include <cstdio>

typedef __attribute__((ext_vector_type(8))) short short8;
typedef __attribute__((ext_vector_type(4))) float f32x4;

// ---------- helpers ----------

__device__ __forceinline__ unsigned short bf16r(float f) {
  union { float f; unsigned int u; } x; x.f = f;
  unsigned int r = x.u + 0x7fffu + ((x.u >> 16) & 1u);
  return (unsigned short)(r >> 16);
}

__device__ __forceinline__ float bf16f(unsigned short h) {
  union { unsigned int u; float f; } x; x.u = ((unsigned int)h) << 16;
  return x.f;
}

__device__ __forceinline__ void gload_lds16(const void* g, void* l) {
  __builtin_amdgcn_global_load_lds((const __attribute__((address_space(1))) void*)g,
                                   (__attribute__((address_space(3))) void*)l,
                                   16, 0, 0);
}

// ---------- q_w [4096][4096] f32 -> qwt2 [4096(j)][8192] bf16: cols 0..4095 = hi(q_w^T), 4096.. = lo ----------

__global__ void transpose_hilo(const float* __restrict__ in, unsigned short* __restrict__ out) {
  __shared__ float tile[64][65];
  const int j0 = blockIdx.x * 64, i0 = blockIdx.y * 64;
  const int tx = threadIdx.x & 15, ty = threadIdx.x >> 4;
  #pragma unroll
  for (int w = 0; w < 4; ++w) {
    int r = ty + w * 16;
    float4 v = *reinterpret_cast<const float4*>(in + (size_t)(i0 + r) * 4096 + j0 + tx * 4);
    tile[r][tx * 4 + 0] = v.x; tile[r][tx * 4 + 1] = v.y;
    tile[r][tx * 4 + 2] = v.z; tile[r][tx * 4 + 3] = v.w;
  }
  __syncthreads();
  #pragma unroll
  for (int w = 0; w < 4; ++w) {
    int r = ty + w * 16;   // j offset within tile
    float v0 = tile[tx * 4 + 0][r], v1 = tile[tx * 4 + 1][r];
    float v2 = tile[tx * 4 + 2][r], v3 = tile[tx * 4 + 3][r];
    ushort4 hi, lo;
    hi.x = bf16r(v0); lo.x = bf16r(v0 - bf16f(hi.x));
    hi.y = bf16r(v1); lo.y = bf16r(v1 - bf16f(hi.y));
    hi.z = bf16r(v2); lo.z = bf16r(v2 - bf16f(hi.z));
    hi.w = bf16r(v3); lo.w = bf16r(v3 - bf16f(hi.w));
    *reinterpret_cast<ushort4*>(out + (size_t)(j0 + r) * 8192 + i0 + tx * 4) = hi;
    *reinterpret_cast<ushort4*>(out + (size_t)(j0 + r) * 8192 + 4096 + i0 + tx * 4) = lo;
  }
}

// ---------- k_cache [100][4096] f32 -> kpad2 [128][8192] bf16 duplicated ([kpad|kpad]), rows>=100 zero ----------

__global__ void build_pad_dup(const float* __restrict__ src, unsigned short* __restrict__ dst) {
  int idx = blockIdx.x * blockDim.x + threadIdx.x;   // over 128*4096
  if (idx >= 128 * 4096) return;
  int l = idx >> 12, i = idx & 4095;
  float v = (l < 100) ? src[idx] : 0.f;
  unsigned short b = bf16r(v);
  dst[(size_t)l * 8192 + i] = b;
  dst[(size_t)l * 8192 + 4096 + i] = b;
}

// ---------- v_cache [100][4096] f32 -> vpad [128][4096] bf16, rows>=100 zero ----------

__global__ void build_pad128(const float* __restrict__ src, unsigned short* __restrict__ dst) {
  int idx = blockIdx.x * blockDim.x + threadIdx.x;
  if (idx >= 128 * 4096) return;
  int row = idx >> 12;
  float v = (row < 100) ? src[idx] : 0.f;
  dst[idx] = bf16r(v);
}

// ---------- sbias[l] = q_b . k_cache[l] (f32, exact), 0 for l>=100 ----------

__global__ void kq_bias(const float* __restrict__ kc, const float* __restrict__ qb,
                        float* __restrict__ sbias) {
  int l = blockIdx.x;            // 0..127
  int lane = threadIdx.x;        // 64
  float s = 0.f;
  if (l < 100) {
    for (int i = lane * 4; i < 4096; i += 256) {
      float4 k = *reinterpret_cast<const float4*>(kc + (size_t)l * 4096 + i);
      float4 q = *reinterpret_cast<const float4*>(qb + i);
      s += k.x * q.x + k.y * q.y + k.z * q.z + k.w * q.w;
    }
  }
  #pragma unroll
  for (int off = 1; off < 64; off <<= 1) s += __shfl_xor(s, off);
  if (lane == 0) sbias[l] = s;
}

// ---------- split-K NT GEMM, bf16 A x bf16 B (both gload_lds) -> f32 partials (KQ GEMM) ----------
// grid (KS, Mtiles, Ntiles); Cpart[ks][M][N]; Kstride = row stride of A and B.

__global__ void gemm_ntk_splitk(const unsigned short* __restrict__ A,
                                const unsigned short* __restrict__ B,
                                float* __restrict__ Cpart,
                                int M, int N, int Kstride, int kchunk) {
  __shared__ unsigned short As[128][32];
  __shared__ unsigned short Bs[128][32];

  const int tid = threadIdx.x, wave = tid >> 6, lane = tid & 63;
  const int wm = wave >> 1, wn = wave & 1;
  const size_t rowA0 = (size_t)blockIdx.y * 128;
  const size_t colB0 = (size_t)blockIdx.z * 128;
  const int k0base = blockIdx.x * kchunk;

  f32x4 acc[4][4] = {};

  const int sr = wave * 16 + (lane >> 2);
  const int sc = (lane & 3) << 3;

  const unsigned short* Ap0 = A + (rowA0 + sr) * (size_t)Kstride + k0base + sc;
  const unsigned short* Ap1 = A + (rowA0 + 64 + sr) * (size_t)Kstride + k0base + sc;
  const unsigned short* Bp0 = B + (colB0 + sr) * (size_t)Kstride + k0base + sc;
  const unsigned short* Bp1 = B + (colB0 + 64 + sr) * (size_t)Kstride + k0base + sc;
  unsigned short* AsD0 = &As[wave * 16][0];
  unsigned short* AsD1 = &As[64 + wave * 16][0];
  unsigned short* BsD0 = &Bs[wave * 16][0];
  unsigned short* BsD1 = &Bs[64 + wave * 16][0];

  const int fr = lane & 15;
  const int fk = (lane >> 4) << 3;

  for (int k0 = 0; k0 < kchunk; k0 += 32) {
    gload_lds16(Ap0 + k0, AsD0);
    gload_lds16(Ap1 + k0, AsD1);
    gload_lds16(Bp0 + k0, BsD0);
    gload_lds16(Bp1 + k0, BsD1);
    __syncthreads();

    short8 av[4], bv[4];
    #pragma unroll
    for (int mi = 0; mi < 4; ++mi)
      av[mi] = *reinterpret_cast<const short8*>(&As[wm * 64 + mi * 16 + fr][fk]);
    #pragma unroll
    for (int ni = 0; ni < 4; ++ni)
      bv[ni] = *reinterpret_cast<const short8*>(&Bs[wn * 64 + ni * 16 + fr][fk]);
    #pragma unroll
    for (int mi = 0; mi < 4; ++mi)
      #pragma unroll
      for (int ni = 0; ni < 4; ++ni)
        acc[mi][ni] = __builtin_amdgcn_mfma_f32_16x16x32_bf16(av[mi], bv[ni], acc[mi][ni], 0, 0, 0);
    __syncthreads();
  }

  float* Cp = Cpart + (size_t)blockIdx.x * M * N;
  const int orow = (lane >> 4) * 4;
  const int ocol = lane & 15;
  #pragma unroll
  for (int mi = 0; mi < 4; ++mi) {
    #pragma unroll
    for (int ni = 0; ni < 4; ++ni) {
      size_t r0 = rowA0 + wm * 64 + mi * 16 + orow;
      size_t c  = colB0 + wn * 64 + ni * 16 + ocol;
      #pragma unroll
      for (int j = 0; j < 4; ++j)
        Cp[(r0 + j) * (size_t)N + c] = acc[mi][ni][j];
    }
  }
}

// ---------- split-K NT GEMM, f32 A (reg-staged cvt) x bf16 B (gload_lds) -> f32 partials ----------
// Round-5 proven structure (2.2 TB/s). blockIdx.x = (ks << ntShift) | ntile.

__global__ void gemm_ntf_splitk(const float* __restrict__ A,
                                const unsigned short* __restrict__ B,
                                float* __restrict__ Cpart,
                                int M, int N, int Kstride, int kchunk, int ntShift) {
  __shared__ unsigned short As[128][32];
  __shared__ unsigned short Bs[128][32];

  const int tid = threadIdx.x, wave = tid >> 6, lane = tid & 63;
  const int wm = wave >> 1, wn = wave & 1;
  const int ks = blockIdx.x >> ntShift;
  const int ntile = blockIdx.x & ((1 << ntShift) - 1);
  const size_t rowA0 = (size_t)blockIdx.y * 128;
  const size_t colB0 = (size_t)ntile * 128;
  const int k0base = ks * kchunk;

  f32x4 acc[4][4] = {};

  // A staging: thread t covers row t>>1, k-half (t&1)*16 (16 f32 -> 16 bf16 per step)
  const int arow = tid >> 1;
  const int ahalf = (tid & 1) * 16;
  const float* Aprow = A + (rowA0 + arow) * (size_t)Kstride + k0base + ahalf;

  const int sr = wave * 16 + (lane >> 2);
  const int sc = (lane & 3) << 3;
  const unsigned short* Bp0 = B + (colB0 + sr) * (size_t)Kstride + k0base + sc;
  const unsigned short* Bp1 = B + (colB0 + 64 + sr) * (size_t)Kstride + k0base + sc;
  unsigned short* BsD0 = &Bs[wave * 16][0];
  unsigned short* BsD1 = &Bs[64 + wave * 16][0];

  const int fr = lane & 15;
  const int fk = (lane >> 4) << 3;

  for (int k0 = 0; k0 < kchunk; k0 += 32) {
    gload_lds16(Bp0 + k0, BsD0);
    gload_lds16(Bp1 + k0, BsD1);
    float4 f0 = *reinterpret_cast<const float4*>(Aprow + k0);
    float4 f1 = *reinterpret_cast<const float4*>(Aprow + k0 + 4);
    float4 f2 = *reinterpret_cast<const float4*>(Aprow + k0 + 8);
    float4 f3 = *reinterpret_cast<const float4*>(Aprow + k0 + 12);
    short8 h0, h1;
    h0[0] = (short)bf16r(f0.x); h0[1] = (short)bf16r(f0.y);
    h0[2] = (short)bf16r(f0.z); h0[3] = (short)bf16r(f0.w);
    h0[4] = (short)bf16r(f1.x); h0[5] = (short)bf16r(f1.y);
    h0[6] = (short)bf16r(f1.z); h0[7] = (short)bf16r(f1.w);
    h1[0] = (short)bf16r(f2.x); h1[1] = (short)bf16r(f2.y);
    h1[2] = (short)bf16r(f2.z); h1[3] = (short)bf16r(f2.w);
    h1[4] = (short)bf16r(f3.x); h1[5] = (short)bf16r(f3.y);
    h1[6] = (short)bf16r(f3.z); h1[7] = (short)bf16r(f3.w);
    *reinterpret_cast<short8*>(&As[arow][ahalf]) = h0;
    *reinterpret_cast<short8*>(&As[arow][ahalf + 8]) = h1;
    __syncthreads();

    short8 av[4], bv[4];
    #pragma unroll
    for (int mi = 0; mi < 4; ++mi)
      av[mi] = *reinterpret_cast<const short8*>(&As[wm * 64 + mi * 16 + fr][fk]);
    #pragma unroll
    for (int ni = 0; ni < 4; ++ni)
      bv[ni] = *reinterpret_cast<const short8*>(&Bs[wn * 64 + ni * 16 + fr][fk]);
    #pragma unroll
    for (int mi = 0; mi < 4; ++mi)
      #pragma unroll
      for (int ni = 0; ni < 4; ++ni)
        acc[mi][ni] = __builtin_amdgcn_mfma_f32_16x16x32_bf16(av[mi], bv[ni], acc[mi][ni], 0, 0, 0);
    __syncthreads();
  }

  float* Cp = Cpart + (size_t)ks * M * N;
  const int orow = (lane >> 4) * 4;
  const int ocol = lane & 15;
  #pragma unroll
  for (int mi = 0; mi < 4; ++mi) {
    #pragma unroll
    for (int ni = 0; ni < 4; ++ni) {
      size_t r0 = rowA0 + wm * 64 + mi * 16 + orow;
      size_t c  = colB0 + wn * 64 + ni * 16 + ocol;
      #pragma unroll
      for (int j = 0; j < 4; ++j)
        Cp[(r0 + j) * (size_t)N + c] = acc[mi][ni][j];
    }
  }
}

// ---------- KQ reduce: sum 8 partials [128][4096], split hi/lo -> KQ2 [256][4096] bf16 ----------

__global__ void kq_reduce(const float* __restrict__ KQpart, unsigned short* __restrict__ KQ2) {
  int idx = blockIdx.x * blockDim.x + threadIdx.x;   // over 128*4096, idx = l*4096 + j
  if (idx >= 128 * 4096) return;
  float s = 0.f;
  #pragma unroll
  for (int ks = 0; ks < 8; ++ks) s += KQpart[(size_t)ks * 128 * 4096 + idx];
  unsigned short hi = bf16r(s);
  unsigned short lo = bf16r(s - bf16f(hi));
  int l = idx >> 12, j = idx & 4095;
  KQ2[(size_t)l * 4096 + j]         = hi;
  KQ2[(size_t)(l + 128) * 4096 + j] = lo;
}

// ---------- softmax: sum 8 ks-partials + hi/lo col fold + bias -> duplicated [W|W] bf16 [rows][256] ----------

__global__ void softmax_fused2(const float* __restrict__ Spart, const float* __restrict__ sbias,
                               unsigned short* __restrict__ W2, int rows) {
  int wave = threadIdx.x >> 6;
  int lane = threadIdx.x & 63;
  int row = blockIdx.x * (blockDim.x >> 6) + wave;
  if (row >= rows) return;
  const float scale = 0.088388347648318447f;   // 1/sqrt(128)
  float sx = 0.f, sy = 0.f;
  #pragma unroll
  for (int ks = 0; ks < 8; ++ks) {
    const float* P = Spart + ((size_t)ks * rows + row) * 256;
    float2 a = reinterpret_cast<const float2*>(P)[lane];          // hi cols
    float2 b = reinterpret_cast<const float2*>(P + 128)[lane];    // lo cols
    sx += a.x + b.x; sy += a.y + b.y;
  }
  float2 bb = reinterpret_cast<const float2*>(sbias)[lane];
  sx += bb.x; sy += bb.y;
  int c0 = lane * 2, c1 = c0 + 1;
  float s0 = (c0 <= 100) ? sx * scale : -1e30f;
  float s1 = (c1 <= 100) ? sy * scale : -1e30f;
  float m = fmaxf(s0, s1);
  #pragma unroll
  for (int off = 1; off < 64; off <<= 1) m = fmaxf(m, __shfl_xor(m, off));
  float e0 = (c0 <= 100) ? __expf(s0 - m) : 0.f;
  float e1 = (c1 <= 100) ? __expf(s1 - m) : 0.f;
  float sum = e0 + e1;
  #pragma unroll
  for (int off = 1; off < 64; off <<= 1) sum += __shfl_xor(sum, off);
  float inv = 1.f / sum;
  ushort2 o;
  o.x = bf16r(e0 * inv);
  o.y = bf16r(e1 * inv);
  reinterpret_cast<ushort2*>(W2 + (size_t)row * 256)[lane] = o;
  reinterpret_cast<ushort2*>(W2 + (size_t)row * 256 + 128)[lane] = o;
}

// ---------- VO reduce: sum 16 partials [4096][128], split hi/lo -> VOT2 [4096][256] bf16 ----------

__global__ void vo_reduce(const float* __restrict__ VOpart, unsigned short* __restrict__ VOT2) {
  int idx = blockIdx.x * blockDim.x + threadIdx.x;   // over 4096*128, idx = o*128 + l
  if (idx >= 4096 * 128) return;
  float s = 0.f;
  #pragma unroll
  for (int ks = 0; ks < 16; ++ks) s += VOpart[(size_t)ks * 4096 * 128 + idx];
  unsigned short hi = bf16r(s);
  unsigned short lo = bf16r(s - bf16f(hi));
  int o = idx >> 7, l = idx & 127;
  VOT2[(size_t)o * 256 + l]       = hi;
  VOT2[(size_t)o * 256 + 128 + l] = lo;
}

// ---------- m97-style 128^2 NT GEMM (final: out = W2 @ VOT2^T + out_b) ----------

template<bool ADD_BIAS, bool OUT_F32>
__global__ void gemm_nt(const unsigned short* __restrict__ A,
                        const unsigned short* __restrict__ B,
                        const float* __restrict__ bias,
                        void* __restrict__ Cout,
                        int M, int N, int K) {
  __shared__ unsigned short As[128][32];
  __shared__ unsigned short Bs[128][32];

  const int tid  = threadIdx.x;
  const int wave = tid >> 6;
  const int lane = tid & 63;
  const int wm = wave >> 1;
  const int wn = wave & 1;
  const size_t rowA0 = (size_t)blockIdx.y * 128;
  const size_t colB0 = (size_t)blockIdx.x * 128;

  f32x4 acc[4][4] = {};

  const int sr = wave * 16 + (lane >> 2);
  const int sc = (lane & 3) << 3;

  const unsigned short* Ap0 = A + (rowA0 + sr) * (size_t)K + sc;
  const unsigned short* Ap1 = A + (rowA0 + 64 + sr) * (size_t)K + sc;
  const unsigned short* Bp0 = B + (colB0 + sr) * (size_t)K + sc;
  const unsigned short* Bp1 = B + (colB0 + 64 + sr) * (size_t)K + sc;
  unsigned short* AsD0 = &As[wave * 16][0];
  unsigned short* AsD1 = &As[64 + wave * 16][0];
  unsigned short* BsD0 = &Bs[wave * 16][0];
  unsigned short* BsD1 = &Bs[64 + wave * 16][0];

  const int fr = lane & 15;
  const int fk = (lane >> 4) << 3;

  for (int k0 = 0; k0 < K; k0 += 32) {
    gload_lds16(Ap0 + k0, AsD0);
    gload_lds16(Ap1 + k0, AsD1);
    gload_lds16(Bp0 + k0, BsD0);
    gload_lds16(Bp1 + k0, BsD1);
    __syncthreads();

    short8 av[4], bv[4];
    #pragma unroll
    for (int mi = 0; mi < 4; ++mi)
      av[mi] = *reinterpret_cast<const short8*>(&As[wm * 64 + mi * 16 + fr][fk]);
    #pragma unroll
    for (int ni = 0; ni < 4; ++ni)
      bv[ni] = *reinterpret_cast<const short8*>(&Bs[wn * 64 + ni * 16 + fr][fk]);
    #pragma unroll
    for (int mi = 0; mi < 4; ++mi)
      #pragma unroll
      for (int ni = 0; ni < 4; ++ni)
        acc[mi][ni] = __builtin_amdgcn_mfma_f32_16x16x32_bf16(av[mi], bv[ni], acc[mi][ni], 0, 0, 0);
    __syncthreads();
  }

  const int orow = (lane >> 4) * 4;
  const int ocol = lane & 15;
  #pragma unroll
  for (int mi = 0; mi < 4; ++mi) {
    #pragma unroll
    for (int ni = 0; ni < 4; ++ni) {
      size_t r0 = rowA0 + wm * 64 + mi * 16 + orow;
      size_t c  = colB0 + wn * 64 + ni * 16 + ocol;
      float bv_ = ADD_BIAS ? bias[c] : 0.f;
      #pragma unroll
      for (int j = 0; j < 4; ++j) {
        float v = acc[mi][ni][j] + bv_;
        if (OUT_F32) ((float*)Cout)[(r0 + j) * (size_t)N + c] = v;
        else         ((unsigned short*)Cout)[(r0 + j) * (size_t)N + c] = bf16r(v);
      }
    }
  }
}

// ---------- launch ----------

extern "C" void kernel_launch(void* const* d_in, const int* in_sizes, int n_in,
                              void* d_out, int out_size, void* d_ws, size_t ws_size,
                              hipStream_t stream) {
  const float* x       = (const float*)d_in[0];   // [8192,4096]
  const float* q_w     = (const float*)d_in[1];   // [4096,4096]
  const float* q_b     = (const float*)d_in[2];   // [4096]
  const float* k_cache = (const float*)d_in[3];   // [100,4096]
  const float* v_cache = (const float*)d_in[4];   // [100,4096]
  const float* out_w   = (const float*)d_in[5];   // [4096,4096]
  const float* out_b   = (const float*)d_in[6];   // [4096]
  float* out = (float*)d_out;

  const int M = 8192, H = 4096;

  char* ws = (char*)d_ws;
  size_t off = 0;
  auto alloc = [&](size_t bytes) { void* p = ws + off; off += (bytes + 255) & ~(size_t)255; return p; };
  unsigned short* qwt2   = (unsigned short*)alloc((size_t)H * 8192 * 2);   // 67 MB  q_w^T hi|lo
  unsigned short* kpad2  = (unsigned short*)alloc((size_t)128 * 8192 * 2); // 2 MB   [kpad|kpad]
  unsigned short* vpad   = (unsigned short*)alloc((size_t)128 * H * 2);    // 1 MB
  float*          sbias  = (float*)alloc(128 * 4);
  unsigned short* KQ2    = (unsigned short*)alloc((size_t)256 * H * 2);    // 2 MB   [KQ_hi;KQ_lo]
  unsigned short* W2     = (unsigned short*)alloc((size_t)M * 256 * 2);    // 4 MB   [W|W]
  unsigned short* VOT2   = (unsigned short*)alloc((size_t)H * 256 * 2);    // 2 MB   [VO^T hi|lo]
  float*          scratch= (float*)alloc((size_t)68 << 20);                // 68 MB  partials
  if (ws_size < off) { fprintf(stderr, "ws too small: need %zu have %zu\n", off, ws_size); return; }

  // 1) weight/cache preprocessing
  transpose_hilo<<<dim3(64, 64), 256, 0, stream>>>(q_w, qwt2);
  build_pad_dup<<<2048, 256, 0, stream>>>(k_cache, kpad2);
  build_pad128<<<2048, 256, 0, stream>>>(v_cache, vpad);
  kq_bias<<<128, 64, 0, stream>>>(k_cache, q_b, sbias);

  // 2) KQ = kpad @ q_w  (via [kpad|kpad] @ [qwt_hi|qwt_lo]^T, K=8192), split-K 8
  gemm_ntk_splitk<<<dim3(8, 1, 32), 256, 0, stream>>>(kpad2, qwt2, scratch, 128, H, 8192, 1024);
  kq_reduce<<<2048, 256, 0, stream>>>(scratch, KQ2);

  // 3) S = x @ KQ2^T (N=256 hi/lo planes), split-K 8 -> 1024 blocks (was 4 -> 512)
  gemm_ntf_splitk<<<dim3(16, 64), 256, 0, stream>>>(x, KQ2, scratch, M, 256, H, 512, 1);

  // 4) softmax (8 ks partials + hi/lo fold + bias) -> W2 [8192][256] dup
  softmax_fused2<<<M / 4, 256, 0, stream>>>(scratch, sbias, W2, M);

  // 5) VO^T = out_w @ vpad^T, split-K 16 -> 512 blocks (was 8 -> 256)
  gemm_ntf_splitk<<<dim3(16, 32), 256, 0, stream>>>(out_w, vpad, scratch, H, 128, H, 256, 0);
  vo_reduce<<<2048, 256, 0, stream>>>(scratch, VOT2);

  // 6) out = W2 @ VOT2^T + out_b  (K=256: [W|W] x [hi|lo])
  gemm_nt<true, true><<<dim3(32, 64), 256, 0, stream>>>(W2, VOT2, out_b, out, M, H, 256);
}